// Round 1
// 3413.553 us; speedup vs baseline: 1.2866x; 1.2866x over previous
//
#include <hip/hip_runtime.h>
#include <cstdint>

#define TT 512

typedef unsigned short u16;
typedef uint32_t u32;
typedef float  floatx4 __attribute__((ext_vector_type(4)));
typedef short  short8  __attribute__((ext_vector_type(8)));
typedef u32    u32x4   __attribute__((ext_vector_type(4)));

__device__ __forceinline__ float bf2f(u16 u) {
    union { u32 i; float f; } v; v.i = ((u32)u) << 16; return v.f;
}
__device__ __forceinline__ u16 f2bf(float f) {
    union { float f; u32 i; } v; v.f = f;
    u32 x = v.i;
    return (u16)((x + 0x7fffu + ((x >> 16) & 1u)) >> 16);  // RNE
}
__device__ __forceinline__ float sigm(float x)  { return 1.0f / (1.0f + __expf(-x)); }
__device__ __forceinline__ float tanh_(float x) { return 2.0f / (1.0f + __expf(-2.0f * x)) - 1.0f; }
#define BF(p) (*(const short8*)(p))

// ---- fine-grain MALL-coherent accesses (sc0 sc1 = bypass L1+L2, coherent at
// the device LLC). No buffer_wbl2 / buffer_inv cache maintenance is needed, so
// the per-XCD L2 (holding the 192 KB/block weight fragments) stays warm across
// all 512 phases. Ordering is manual: s_waitcnt vmcnt(0) = wave's stores acked
// at the coherence point.
__device__ __forceinline__ void st_u32_coh(u32* p, u32 v) {
    asm volatile("global_store_dword %0, %1, off sc0 sc1" :: "v"(p), "v"(v) : "memory");
}
__device__ __forceinline__ void st_f32_coh(float* p, float v) {
    asm volatile("global_store_dword %0, %1, off sc0 sc1" :: "v"(p), "v"(v) : "memory");
}
__device__ __forceinline__ u32 ld_u32_coh(const u32* p) {          // self-waiting (poll)
    u32 v;
    asm volatile("global_load_dword %0, %1, off sc0 sc1\n\ts_waitcnt vmcnt(0)"
                 : "=v"(v) : "v"(p) : "memory");
    return v;
}
__device__ __forceinline__ u32x4 ld_u128_coh(const u32x4* p) {     // pipelined: no wait
    u32x4 v;
    asm volatile("global_load_dwordx4 %0, %1, off sc0 sc1" : "=v"(v) : "v"(p));
    return v;
}
__device__ __forceinline__ float ld_f32_coh(const float* p) {      // pipelined: no wait
    float v;
    asm volatile("global_load_dword %0, %1, off sc0 sc1" : "=v"(v) : "v"(p));
    return v;
}
__device__ __forceinline__ void vmcnt0() { asm volatile("s_waitcnt vmcnt(0)" ::: "memory"); }
#define KEEP(x) asm volatile("" : "+v"(x))   // consume-after-wait fence (rule #18)

__global__ void zero_flags(u32* flg) { st_u32_coh(&flg[threadIdx.x], 0u); }   // 128 words

#define MFMA_(A_, B_, ACC) ACC = __builtin_amdgcn_mfma_f32_16x16x32_bf16(A_, B_, ACC, 0, 0, 0)
#define MS1(ACC, GATE_) { short8 A_ = BF(fs0 + (GATE_) * 4096); \
    MFMA_(A_, Bh, ACC); MFMA_(A_, Bl, ACC); }
#define MS3(ACC, GATE_) { short8 A1_ = BF(fs1 + (GATE_) * 4096); \
    MFMA_(A1_, Bh, ACC); MFMA_(A1_, Bl, ACC); \
    short8 A2_ = BF(fs2 + (GATE_) * 4096); \
    MFMA_(A2_, Ch, ACC); MFMA_(A2_, Cl, ACC); }

// layer-0 gate: update c0, publish packed h0(p+1) via sc0sc1 write-through store
#define GATE0(R) { \
    const int d_ = dg16 + 4 * q + (R); \
    float zi_ = Zi[R] + b0s[0][d_], zf_ = Zf[R] + b0s[1][d_]; \
    float zg_ = Zg[R] + b0s[2][d_], zo_ = Zo[R] + b0s[3][d_]; \
    float c_  = sigm(zf_) * c0v[R] + sigm(zi_) * tanh_(zg_); c0v[R] = c_; \
    float hv_ = sigm(zo_) * tanh_(c_); \
    u16 hi_ = f2bf(hv_); u16 lo_ = f2bf(hv_ - bf2f(hi_)); \
    st_u32_coh(&hx0w[d_ * 16 + bq], ((u32)hi_ << 16) | (u32)lo_); }
#define GATE1L(R) { \
    const int d_ = dg16 + 4 * q + (R); \
    float zi_ = Yi[R] + b1s[0][d_], zf_ = Yf[R] + b1s[1][d_]; \
    float zg_ = Yg[R] + b1s[2][d_], zo_ = Yo[R] + b1s[3][d_]; \
    float c_  = sigm(zf_) * c1v[R] + sigm(zi_) * tanh_(zg_); c1v[R] = c_; \
    float hv_ = sigm(zo_) * tanh_(c_); \
    u16 hi_ = f2bf(hv_); u16 lo_ = f2bf(hv_ - bf2f(hi_)); \
    st_u32_coh(&hx1w[d_ * 16 + bq], ((u32)hi_ << 16) | (u32)lo_); \
    part += hv_ * who_s[d_]; }

#define UNPACK0(v, i4) { const int d_ = (i4) >> 2, bb_ = ((i4) & 3) * 4; \
    h0hi[bb_ + 0][d_] = (short)((v)[0] >> 16); h0lo[bb_ + 0][d_] = (short)((v)[0] & 0xFFFFu); \
    h0hi[bb_ + 1][d_] = (short)((v)[1] >> 16); h0lo[bb_ + 1][d_] = (short)((v)[1] & 0xFFFFu); \
    h0hi[bb_ + 2][d_] = (short)((v)[2] >> 16); h0lo[bb_ + 2][d_] = (short)((v)[2] & 0xFFFFu); \
    h0hi[bb_ + 3][d_] = (short)((v)[3] >> 16); h0lo[bb_ + 3][d_] = (short)((v)[3] & 0xFFFFu); }
#define UNPACK1(v, i4) { const int d_ = (i4) >> 2, bb_ = ((i4) & 3) * 4; \
    h1hi[bb_ + 0][d_] = (short)((v)[0] >> 16); h1lo[bb_ + 0][d_] = (short)((v)[0] & 0xFFFFu); \
    h1hi[bb_ + 1][d_] = (short)((v)[1] >> 16); h1lo[bb_ + 1][d_] = (short)((v)[1] & 0xFFFFu); \
    h1hi[bb_ + 2][d_] = (short)((v)[2] >> 16); h1lo[bb_ + 2][d_] = (short)((v)[2] & 0xFFFFu); \
    h1hi[bb_ + 3][d_] = (short)((v)[3] >> 16); h1lo[bb_ + 3][d_] = (short)((v)[3] & 0xFFFFu); }

// 128 blocks = 16 groups x 8 dim-slices. Skewed pipeline.
// Exchange protocol per phase (fine-grain coherent, NO wbl2/inv):
//   sc0sc1 data stores -> per-wave s_waitcnt vmcnt(0) -> __syncthreads
//   -> wave0: posc sc0sc1 stores, wave-level vmcnt(0), flag sc0sc1 store
//   readers: spin on sc0sc1 loads (always fetch LLC) -> __syncthreads
//   -> pipelined sc0sc1 dwordx4 readback -> vmcnt(0) -> unpack to LDS.
__launch_bounds__(256, 2)
__global__ void lstm_skew(const float* __restrict__ latent, const float* __restrict__ W_lh,
                          const float* __restrict__ b_lh,
                          const float* __restrict__ W_hh0,
                          const float* __restrict__ b_ih0, const float* __restrict__ b_hh0,
                          const float* __restrict__ W_ih1, const float* __restrict__ W_hh1,
                          const float* __restrict__ b_ih1, const float* __restrict__ b_hh1,
                          const float* __restrict__ W_ho,  const float* __restrict__ b_ho,
                          short* __restrict__ frag, u32* __restrict__ hx0, u32* __restrict__ hx1,
                          float* __restrict__ posc, u32* __restrict__ flg,
                          float* __restrict__ out)
{
    __shared__ __align__(16) short h0hi[16][264], h0lo[16][264];   // h0(p), full 256 dims
    __shared__ __align__(16) short h1hi[16][264], h1lo[16][264];   // h1(p-1)
    __shared__ float b0s[4][256], b1s[4][256];
    __shared__ float who_s[256];
    __shared__ float osc[2][16];

    const int tid  = threadIdx.x;      // 256 threads, 4 waves
    const int w    = tid >> 6;
    const int lane = tid & 63;
    const int bq   = lane & 15;
    const int q    = lane >> 4;
    const int g    = blockIdx.x & 15;  // batch group
    const int j    = blockIdx.x >> 4;  // dim slice 0..7
    const int bglo = g * 16;

    // ---- stage this slice's weight fragments (identical bytes across groups: benign race)
    for (int i = tid; i < 12288; i += 256) {
        const int l8 = i & 63, s8 = (i >> 6) & 7, gate8 = (i >> 9) & 3;
        const int dgl = (i >> 11) & 1, G = i >> 12;
        const int dgw = 2 * j + dgl;
        const float* W = (G == 0) ? W_hh0 : (G == 1) ? W_ih1 : W_hh1;
        const float* src = W + (gate8 * 256 + dgw * 16 + (l8 & 15)) * 256
                             + s8 * 32 + (l8 >> 4) * 8;
        short8 v;
#pragma unroll
        for (int jj = 0; jj < 8; ++jj) v[jj] = (short)f2bf(src[jj]);
        *(short8*)(frag + (size_t)(l8 * 8 + s8 * 512 + gate8 * 4096 + dgw * 16384 + G * 262144)) = v;
    }
    for (int i = tid; i < 1024; i += 256) {
        b0s[i >> 8][i & 255] = b_ih0[i] + b_hh0[i];
        b1s[i >> 8][i & 255] = b_ih1[i] + b_hh1[i];
    }
    if (tid < 256) who_s[tid] = W_ho[tid];

    // h_init = latent @ W_lh.T + b_lh (fp32), split hi/lo
    {
        const int b = tid >> 4, d0 = (tid & 15) * 16;
        const float* lr = latent + (bglo + b) * 128;
#pragma unroll
        for (int jj = 0; jj < 16; ++jj) {
            const int d = d0 + jj;
            const float* wr = W_lh + d * 128;
            float acc = b_lh[d];
            for (int c = 0; c < 128; c += 4) {
                float4 lv = *(const float4*)(lr + c);
                float4 wv = *(const float4*)(wr + c);
                acc += lv.x * wv.x + lv.y * wv.y + lv.z * wv.z + lv.w * wv.w;
            }
            u16 hi = f2bf(acc), lo = f2bf(acc - bf2f(hi));
            h0hi[b][d] = (short)hi; h0lo[b][d] = (short)lo;
            h1hi[b][d] = (short)hi; h1lo[b][d] = (short)lo;
        }
    }
    __syncthreads();

    // wave roles: w0,w1 = layer 0 (dim-groups 2j, 2j+1); w2,w3 = layer 1
    const int dgw   = 2 * j + (w & 1);
    const int dg16  = dgw * 16;
    const short* fb0 = frag + dgw * 16384 + (size_t)lane * 8;
    const short* fb1 = frag + 262144 + dgw * 16384 + (size_t)lane * 8;
    const short* fb2 = fb1 + 262144;
    u32* myflag = flg + g * 8 + j;
    float c0v[4] = {0.f, 0.f, 0.f, 0.f}, c1v[4] = {0.f, 0.f, 0.f, 0.f};
    const float bho = b_ho[0];

    for (int p = 0; p <= TT; ++p) {
        const int pb = p & 1;
        u32* hx0w = hx0 + pb * 65536 + g * 4096;
        u32* hx1w = hx1 + pb * 65536 + g * 4096;

        if (w < 2 && p < TT) {          // layer 0
            floatx4 Zi = {0.f,0.f,0.f,0.f}, Zf = {0.f,0.f,0.f,0.f};
            floatx4 Zg = {0.f,0.f,0.f,0.f}, Zo = {0.f,0.f,0.f,0.f};
#pragma unroll 1
            for (int s = 0; s < 8; ++s) {
                const int hoff = s * 32 + q * 8;
                short8 Bh = BF(&h0hi[bq][hoff]);
                short8 Bl = BF(&h0lo[bq][hoff]);
                const short* fs0 = fb0 + s * 512;
                MS1(Zi, 0) MS1(Zf, 1) MS1(Zg, 2) MS1(Zo, 3)
            }
            GATE0(0) GATE0(1) GATE0(2) GATE0(3)
        }
        if (w >= 2 && p >= 1) {         // layer 1
            floatx4 Yi = {0.f,0.f,0.f,0.f}, Yf = {0.f,0.f,0.f,0.f};
            floatx4 Yg = {0.f,0.f,0.f,0.f}, Yo = {0.f,0.f,0.f,0.f};
#pragma unroll 1
            for (int s = 0; s < 8; ++s) {
                const int hoff = s * 32 + q * 8;
                short8 Bh = BF(&h0hi[bq][hoff]);
                short8 Bl = BF(&h0lo[bq][hoff]);
                short8 Ch = BF(&h1hi[bq][hoff]);
                short8 Cl = BF(&h1lo[bq][hoff]);
                const short* fs1 = fb1 + s * 512;
                const short* fs2 = fb2 + s * 512;
                MS3(Yi, 0) MS3(Yf, 1) MS3(Yg, 2) MS3(Yo, 3)
            }
            float part = 0.0f;
            GATE1L(0) GATE1L(1) GATE1L(2) GATE1L(3)
            part += __shfl_xor(part, 16, 64);
            part += __shfl_xor(part, 32, 64);
            if (q == 0) osc[w - 2][bq] = part;
        }
        vmcnt0();                        // every wave: its hx stores acked at LLC
        __syncthreads();                 // osc visible in LDS; all waves drained
        if (p >= 1 && tid < 16)
            st_f32_coh(posc + pb * 2048 + g * 128 + j * 16 + tid, osc[0][tid] + osc[1][tid]);
        if (tid == 0) {                  // wave-level waitcnt drains lanes 0..15 posc stores
            vmcnt0();
            st_u32_coh(myflag, (u32)(p + 1));
        }
        if (tid < 8) {                   // spin on LLC-coherent loads; no cache inv
            const u32 tgt = (u32)(p + 1);
            int it = 0;
            while (ld_u32_coh(flg + g * 8 + tid) < tgt) {
                __builtin_amdgcn_s_sleep(1);
                if (++it > 50000) break; // finite-wrong, never hang
            }
        }
        __syncthreads();
        // ---- pipelined coherent readback: h0(p+1), h1(p)
        u32x4 va0, va1, va2, va3, vb0, vb1, vb2, vb3;
        float po0, po1, po2, po3, po4, po5, po6, po7;
        const u32x4* s4a = (const u32x4*)hx0w;
        const u32x4* s4b = (const u32x4*)hx1w;
        const bool doout = (p >= 1) && (j == 0) && (tid < 16);
        if (p < TT) {
            va0 = ld_u128_coh(s4a + tid);
            va1 = ld_u128_coh(s4a + tid + 256);
            va2 = ld_u128_coh(s4a + tid + 512);
            va3 = ld_u128_coh(s4a + tid + 768);
        }
        if (p >= 1) {
            vb0 = ld_u128_coh(s4b + tid);
            vb1 = ld_u128_coh(s4b + tid + 256);
            vb2 = ld_u128_coh(s4b + tid + 512);
            vb3 = ld_u128_coh(s4b + tid + 768);
        }
        if (doout) {
            const float* pp = posc + pb * 2048 + g * 128 + tid;
            po0 = ld_f32_coh(pp);       po1 = ld_f32_coh(pp + 16);
            po2 = ld_f32_coh(pp + 32);  po3 = ld_f32_coh(pp + 48);
            po4 = ld_f32_coh(pp + 64);  po5 = ld_f32_coh(pp + 80);
            po6 = ld_f32_coh(pp + 96);  po7 = ld_f32_coh(pp + 112);
        }
        vmcnt0();                        // all readback loads complete
        if (p < TT) {
            KEEP(va0); KEEP(va1); KEEP(va2); KEEP(va3);
            UNPACK0(va0, tid); UNPACK0(va1, tid + 256);
            UNPACK0(va2, tid + 512); UNPACK0(va3, tid + 768);
        }
        if (p >= 1) {
            KEEP(vb0); KEEP(vb1); KEEP(vb2); KEEP(vb3);
            UNPACK1(vb0, tid); UNPACK1(vb1, tid + 256);
            UNPACK1(vb2, tid + 512); UNPACK1(vb3, tid + 768);
        }
        if (doout) {                     // assemble out[t = p-1]
            KEEP(po0); KEEP(po1); KEEP(po2); KEEP(po3);
            KEEP(po4); KEEP(po5); KEEP(po6); KEEP(po7);
            float o = bho + ((po0 + po1) + (po2 + po3)) + ((po4 + po5) + (po6 + po7));
            out[(bglo + tid) * TT + (p - 1)] = o;
        }
        __syncthreads();                 // LDS h planes ready for next phase
    }
}

extern "C" void kernel_launch(void* const* d_in, const int* in_sizes, int n_in,
                              void* d_out, int out_size, void* d_ws, size_t ws_size,
                              hipStream_t stream)
{
    const float* latent = (const float*)d_in[0];
    const float* W_lh   = (const float*)d_in[1];
    const float* b_lh   = (const float*)d_in[2];
    // d_in[3] = W_ih0: unused (layer-0 inputs are all-zero)
    const float* W_hh0  = (const float*)d_in[4];
    const float* b_ih0  = (const float*)d_in[5];
    const float* b_hh0  = (const float*)d_in[6];
    const float* W_ih1  = (const float*)d_in[7];
    const float* W_hh1  = (const float*)d_in[8];
    const float* b_ih1  = (const float*)d_in[9];
    const float* b_hh1  = (const float*)d_in[10];
    const float* W_ho   = (const float*)d_in[11];
    const float* b_ho   = (const float*)d_in[12];

    char* ws = (char*)d_ws;
    short* frag = (short*)ws;                     // 1,572,864 B
    u32*   hx0  = (u32*)(ws + 1572864);           //   524,288 B (2 parities)
    u32*   hx1  = (u32*)(ws + 2097152);           //   524,288 B
    float* posc = (float*)(ws + 2621440);         //    16,384 B (2 parities)
    u32*   flg  = (u32*)(ws + 2637824);           //       512 B   (total ~2.52 MB)

    zero_flags<<<dim3(1), dim3(128), 0, stream>>>(flg);
    lstm_skew<<<dim3(128), dim3(256), 0, stream>>>(latent, W_lh, b_lh,
                                                   W_hh0, b_ih0, b_hh0,
                                                   W_ih1, W_hh1, b_ih1, b_hh1,
                                                   W_ho, b_ho,
                                                   frag, hx0, hx1, posc, flg,
                                                   (float*)d_out);
}